// Round 1
// baseline (186.194 us; speedup 1.0000x reference)
//
#include <hip/hip_runtime.h>
#include <hip/hip_bf16.h>
#include <stdint.h>

// ConvMoE: B=32, C=384, H=W=28, E=4, HID=384, K=2
// N tokens = 25088. Restructured as two big bf16 MFMA GEMMs:
//   GEMM1: [25088,384] x [1536,384]^T -> hdnS (coef*relu fused, bf16)
//   GEMM2: [25088,1536] x [384,1536]^T -> out (fp32) + sum_e coef*b2
#define B_DIM 32
#define C_DIM 384
#define HW_DIM 784
#define E_DIM 4
#define HID_DIM 384
#define NTOK (B_DIM * HW_DIM)   // 25088
#define NH (E_DIM * HID_DIM)    // 1536

using short8 = __attribute__((ext_vector_type(8))) short;
using f32x4  = __attribute__((ext_vector_type(4))) float;

__device__ __forceinline__ unsigned short f2bf(float f) {
  __hip_bfloat16 h = __float2bfloat16(f);
  return __builtin_bit_cast(unsigned short, h);
}

__device__ __forceinline__ void gload_lds16(const void* g, void* l) {
  __builtin_amdgcn_global_load_lds(
      (const __attribute__((address_space(1))) unsigned int*)g,
      (__attribute__((address_space(3))) unsigned int*)l, 16, 0, 0);
}

// ---------------- kernel 1: weight convert (+ zero present mask) -------------
__global__ __launch_bounds__(256) void prep_kernel(
    const float* __restrict__ w1, const float* __restrict__ w2,
    unsigned short* __restrict__ W1b, unsigned short* __restrict__ W2b,
    unsigned int* __restrict__ present) {
  int i = blockIdx.x * 256 + threadIdx.x;
  if (i == 0) *present = 0u;
  if (i < NH * C_DIM) {
    // W1b[n][c] = w1 flat (already [e*HID+d][c])
    W1b[i] = f2bf(w1[i]);
    // W2b[o][e*384+k] = w2[e][o][k]
    int o = i / NH;
    int r = i - o * NH;
    int e = r / HID_DIM;
    int k = r - e * HID_DIM;
    W2b[i] = f2bf(w2[((size_t)e * C_DIM + o) * HID_DIM + k]);
  }
}

// ---------------- kernel 2: gate + softmax + top2 + x -> bf16 [N][C] ---------
__global__ __launch_bounds__(256) void gate_kernel(
    const float* __restrict__ x, const float* __restrict__ gw,
    const float* __restrict__ gb, unsigned short* __restrict__ xb,
    float* __restrict__ topw, unsigned int* __restrict__ present) {
  __shared__ __align__(16) unsigned short lxs[64][392];  // 64 tok x 384c, row 784B
  __shared__ float pscore[4][64][4];
  __shared__ unsigned int pmask;
  const int b = blockIdx.x;
  const int p0 = blockIdx.y * 64;
  const int cnt = min(64, HW_DIM - p0);   // 64 or 16 (784 = 12*64+16)
  const int tid = threadIdx.x;
  const int cg = tid >> 6, tl = tid & 63;
  if (tid == 0) pmask = 0u;
  float a0 = 0.f, a1 = 0.f, a2 = 0.f, a3 = 0.f;
  const bool valid = tl < cnt;
  if (valid) {
    const float* xp = x + (size_t)b * C_DIM * HW_DIM + p0 + tl;
    for (int c = cg; c < C_DIM; c += 4) {
      const float v = xp[(size_t)c * HW_DIM];     // coalesced over tl
      lxs[tl][c] = f2bf(v);
      const float4 g = *(const float4*)&gw[c * 4];
      a0 += v * g.x; a1 += v * g.y; a2 += v * g.z; a3 += v * g.w;
    }
  }
  pscore[cg][tl][0] = a0; pscore[cg][tl][1] = a1;
  pscore[cg][tl][2] = a2; pscore[cg][tl][3] = a3;
  __syncthreads();
  if (cg == 0 && valid) {
    float z[4];
#pragma unroll
    for (int e = 0; e < 4; e++)
      z[e] = pscore[0][tl][e] + pscore[1][tl][e] + pscore[2][tl][e] +
             pscore[3][tl][e] + gb[e];
    const float mx = fmaxf(fmaxf(z[0], z[1]), fmaxf(z[2], z[3]));
    float s[4]; float sum = 0.f;
#pragma unroll
    for (int e = 0; e < 4; e++) { s[e] = __expf(z[e] - mx); sum += s[e]; }
    const float inv = 1.f / sum;
#pragma unroll
    for (int e = 0; e < 4; e++) s[e] *= inv;
    // top-2, lowest index on ties (strict >)
    int e0 = 0; float v0 = s[0];
#pragma unroll
    for (int e = 1; e < 4; e++) if (s[e] > v0) { v0 = s[e]; e0 = e; }
    int e1 = -1; float v1 = -1.f;
#pragma unroll
    for (int e = 0; e < 4; e++) if (e != e0 && s[e] > v1) { v1 = s[e]; e1 = e; }
    const float r = __expf(v1 - v0);         // <= 1
    const float w0 = 1.f / (1.f + r);        // renormalized softmax of (v0,v1)
    const int m = b * HW_DIM + p0 + tl;
    topw[m * 2] = w0;
    topw[m * 2 + 1] = 1.f - w0;
    atomicOr(&pmask, (1u << e0) | (1u << (4 + e1)));
  }
  __syncthreads();
  if (tid == 0) atomicOr(present, pmask);
  // coalesced bf16 write-out of the transposed tile
  const int nchunk = cnt * 48;               // 48 x 16B per 384-elem row
  for (int ci = tid; ci < nchunk; ci += 256) {
    const int row = ci / 48, c8 = ci - row * 48;
    short8 v = *(const short8*)&lxs[row][c8 * 8];
    *(short8*)&xb[(size_t)(b * HW_DIM + p0 + row) * C_DIM + c8 * 8] = v;
  }
}

// ---------------- kernel 3/4: 128x128 bf16 MFMA GEMM (m97 structure) ---------
// C[M,Ncols] = A[M,K] * Bw[Ncols,K]^T ; EPI 0: hdnS epilogue, 1: out epilogue
template <int KDIM, int EPI>
__global__ __launch_bounds__(256) void gemm_kernel(
    const unsigned short* __restrict__ A, const unsigned short* __restrict__ Bw,
    const float* __restrict__ bias, const float* __restrict__ topw,
    const unsigned int* __restrict__ presentp,
    unsigned short* __restrict__ hOut, float* __restrict__ outp) {
  __shared__ __align__(16) unsigned short As[128 * 32];
  __shared__ __align__(16) unsigned short Bs[128 * 32];
  const int m0 = blockIdx.x * 128;
  const int n0 = blockIdx.y * 128;
  const int tid = threadIdx.x;
  const int lane = tid & 63;
  const int wid = tid >> 6;
  const int wm = wid >> 1, wn = wid & 1;
  f32x4 acc[4][4] = {};
  const int r0 = tid >> 2, kq0 = tid & 3;
  const int ci1 = tid + 256;
  const int r1 = ci1 >> 2, kq1 = ci1 & 3;
  for (int kt = 0; kt < KDIM / 32; ++kt) {
    const int kb = kt * 32;
    gload_lds16(&A[(size_t)(m0 + r0) * KDIM + kb + kq0 * 8], &As[tid * 8]);
    gload_lds16(&A[(size_t)(m0 + r1) * KDIM + kb + kq1 * 8], &As[ci1 * 8]);
    gload_lds16(&Bw[(size_t)(n0 + r0) * KDIM + kb + kq0 * 8], &Bs[tid * 8]);
    gload_lds16(&Bw[(size_t)(n0 + r1) * KDIM + kb + kq1 * 8], &Bs[ci1 * 8]);
    __syncthreads();
    short8 af[4], bfr[4];
    const int rA = wm * 64 + (lane & 15);
    const int rB = wn * 64 + (lane & 15);
    const int ko = (lane >> 4) * 8;
#pragma unroll
    for (int i = 0; i < 4; i++) af[i] = *(const short8*)&As[(rA + i * 16) * 32 + ko];
#pragma unroll
    for (int i = 0; i < 4; i++) bfr[i] = *(const short8*)&Bs[(rB + i * 16) * 32 + ko];
#pragma unroll
    for (int mi = 0; mi < 4; mi++)
#pragma unroll
      for (int ni = 0; ni < 4; ni++)
        acc[mi][ni] = __builtin_amdgcn_mfma_f32_16x16x32_bf16(
            af[mi], bfr[ni], acc[mi][ni], 0, 0, 0);
    __syncthreads();
  }
  const unsigned int pm = *presentp;
  if (EPI == 0) {
    // hdnS[m][n] = bf16( coef[e,m] * relu(acc + b1[e][d]) ), via LDS transpose
    const int e = n0 / HID_DIM;
    const float P0 = (float)((pm >> e) & 1u);
    const float P1 = (float)((pm >> (4 + e)) & 1u);
    const float* b1p = bias + e * HID_DIM + (n0 % HID_DIM);
    unsigned short(*eL)[128] = (unsigned short(*)[128])As;  // 32x128 slab
#pragma unroll
    for (int s = 0; s < 4; s++) {
      if (wm == (s >> 1)) {
#pragma unroll
        for (int mh = 0; mh < 2; ++mh) {
          const int mi = (s & 1) * 2 + mh;
          const int mbase = m0 + s * 32 + mh * 16 + (lane >> 4) * 4;
          const float4 t0 = *(const float4*)&topw[mbase * 2];
          const float4 t1 = *(const float4*)&topw[mbase * 2 + 4];
          const float cj[4] = {P0 * t0.x + P1 * t0.y, P0 * t0.z + P1 * t0.w,
                               P0 * t1.x + P1 * t1.y, P0 * t1.z + P1 * t1.w};
#pragma unroll
          for (int ni = 0; ni < 4; ni++) {
            const int nrel = wn * 64 + ni * 16 + (lane & 15);
            const float bv = b1p[nrel];
#pragma unroll
            for (int j = 0; j < 4; j++) {
              float v = acc[mi][ni][j] + bv;
              v = fmaxf(v, 0.f);
              eL[mh * 16 + (lane >> 4) * 4 + j][nrel] = f2bf(cj[j] * v);
            }
          }
        }
      }
      __syncthreads();
      for (int ci = tid; ci < 512; ci += 256) {
        const int rr = ci >> 4, c8 = ci & 15;
        short8 v = *(const short8*)&eL[rr][c8 * 8];
        *(short8*)&hOut[(size_t)(m0 + s * 32 + rr) * NH + n0 + c8 * 8] = v;
      }
      __syncthreads();
    }
  } else {
    // out[b,o,p] = acc + tw0*Bsum0[o] + tw1*Bsum1[o], float4 along p
    float B0[4], B1[4];
#pragma unroll
    for (int ni = 0; ni < 4; ni++) {
      const int o = n0 + wn * 64 + ni * 16 + (lane & 15);
      float s0 = 0.f, s1 = 0.f;
#pragma unroll
      for (int e2 = 0; e2 < 4; e2++) {
        const float bb = bias[e2 * C_DIM + o];
        s0 += (float)((pm >> e2) & 1u) * bb;
        s1 += (float)((pm >> (4 + e2)) & 1u) * bb;
      }
      B0[ni] = s0; B1[ni] = s1;
    }
#pragma unroll
    for (int mi = 0; mi < 4; mi++) {
      const int mbase = m0 + wm * 64 + mi * 16 + (lane >> 4) * 4;
      const float4 t0 = *(const float4*)&topw[mbase * 2];
      const float4 t1 = *(const float4*)&topw[mbase * 2 + 4];
      const int bb2 = mbase / HW_DIM;
      const int p = mbase - bb2 * HW_DIM;   // 4 consecutive p, same batch
#pragma unroll
      for (int ni = 0; ni < 4; ni++) {
        const int o = n0 + wn * 64 + ni * 16 + (lane & 15);
        float4 v;
        v.x = acc[mi][ni][0] + t0.x * B0[ni] + t0.y * B1[ni];
        v.y = acc[mi][ni][1] + t0.z * B0[ni] + t0.w * B1[ni];
        v.z = acc[mi][ni][2] + t1.x * B0[ni] + t1.y * B1[ni];
        v.w = acc[mi][ni][3] + t1.z * B0[ni] + t1.w * B1[ni];
        *(float4*)&outp[((size_t)bb2 * C_DIM + o) * HW_DIM + p] = v;
      }
    }
  }
}

extern "C" void kernel_launch(void* const* d_in, const int* in_sizes, int n_in,
                              void* d_out, int out_size, void* d_ws, size_t ws_size,
                              hipStream_t stream) {
  const float* x  = (const float*)d_in[0];
  const float* gw = (const float*)d_in[1];
  const float* gb = (const float*)d_in[2];
  const float* w1 = (const float*)d_in[3];
  const float* b1 = (const float*)d_in[4];
  const float* w2 = (const float*)d_in[5];
  const float* b2 = (const float*)d_in[6];
  float* out = (float*)d_out;

  // workspace carve (~94.3 MiB total)
  char* ws = (char*)d_ws;
  unsigned short* xb = (unsigned short*)ws;   ws += (size_t)NTOK * C_DIM * 2;
  unsigned short* hdnS = (unsigned short*)ws; ws += (size_t)NTOK * NH * 2;
  unsigned short* W1b = (unsigned short*)ws;  ws += (size_t)NH * C_DIM * 2;
  unsigned short* W2b = (unsigned short*)ws;  ws += (size_t)C_DIM * NH * 2;
  float* topw = (float*)ws;                   ws += (size_t)NTOK * 2 * 4;
  unsigned int* present = (unsigned int*)ws;

  prep_kernel<<<dim3((NH * C_DIM) / 256), dim3(256), 0, stream>>>(
      w1, w2, W1b, W2b, present);
  gate_kernel<<<dim3(B_DIM, 13), dim3(256), 0, stream>>>(
      x, gw, gb, xb, topw, present);
  gemm_kernel<C_DIM, 0><<<dim3(NTOK / 128, NH / 128), dim3(256), 0, stream>>>(
      xb, W1b, b1, topw, present, hdnS, nullptr);
  gemm_kernel<NH, 1><<<dim3(NTOK / 128, C_DIM / 128), dim3(256), 0, stream>>>(
      hdnS, W2b, b2, topw, present, nullptr, out);
}

// Round 2
// 156.150 us; speedup vs baseline: 1.1924x; 1.1924x over previous
//
#include <hip/hip_runtime.h>
#include <hip/hip_bf16.h>
#include <stdint.h>

// ConvMoE: B=32, C=384, H=W=28, E=4, HID=384, K=2. N tokens = 25088.
// GEMM1: [25088,384] x [1536,384]^T -> hdnS (coef*relu fused, bf16)
// GEMM2: [25088,1536] x [384,1536]^T -> out (fp32) + sum_e coef*b2
#define B_DIM 32
#define C_DIM 384
#define HW_DIM 784
#define E_DIM 4
#define HID_DIM 384
#define NTOK (B_DIM * HW_DIM)   // 25088
#define NH (E_DIM * HID_DIM)    // 1536

using short8 = __attribute__((ext_vector_type(8))) short;
using f32x4  = __attribute__((ext_vector_type(4))) float;
typedef unsigned short ushort_t;

__device__ __forceinline__ ushort_t f2bf(float f) {
  __hip_bfloat16 h = __float2bfloat16(f);
  return __builtin_bit_cast(ushort_t, h);
}

__device__ __forceinline__ void gload_lds16(const void* g, void* l) {
  __builtin_amdgcn_global_load_lds(
      (const __attribute__((address_space(1))) unsigned int*)g,
      (__attribute__((address_space(3))) unsigned int*)l, 16, 0, 0);
}

// ---------------- kernel 1: weight convert (+ zero present mask) -------------
__global__ __launch_bounds__(256) void prep_kernel(
    const float* __restrict__ w1, const float* __restrict__ w2,
    ushort_t* __restrict__ W1b, ushort_t* __restrict__ W2b,
    unsigned int* __restrict__ present) {
  int i = blockIdx.x * 256 + threadIdx.x;
  if (i == 0) *present = 0u;
  if (i < NH * C_DIM) {
    W1b[i] = f2bf(w1[i]);                       // [e*HID+d][c]
    int o = i / NH;
    int r = i - o * NH;
    int e = r / HID_DIM;
    int k = r - e * HID_DIM;
    W2b[i] = f2bf(w2[((size_t)e * C_DIM + o) * HID_DIM + k]);  // [o][e*384+k]
  }
}

// ---------------- kernel 2: gate + softmax + top2 + x -> bf16 [N][C] ---------
__global__ __launch_bounds__(256) void gate_kernel(
    const float* __restrict__ x, const float* __restrict__ gw,
    const float* __restrict__ gb, ushort_t* __restrict__ xb,
    float* __restrict__ topw, unsigned int* __restrict__ present) {
  __shared__ __align__(16) ushort_t lxs[64][392];
  __shared__ float pscore[4][64][4];
  __shared__ unsigned int pmask;
  const int b = blockIdx.x;
  const int p0 = blockIdx.y * 64;
  const int cnt = min(64, HW_DIM - p0);
  const int tid = threadIdx.x;
  const int cg = tid >> 6, tl = tid & 63;
  if (tid == 0) pmask = 0u;
  float a0 = 0.f, a1 = 0.f, a2 = 0.f, a3 = 0.f;
  const bool valid = tl < cnt;
  if (valid) {
    const float* xp = x + (size_t)b * C_DIM * HW_DIM + p0 + tl;
    for (int c = cg; c < C_DIM; c += 4) {
      const float v = xp[(size_t)c * HW_DIM];
      lxs[tl][c] = f2bf(v);
      const float4 g = *(const float4*)&gw[c * 4];
      a0 += v * g.x; a1 += v * g.y; a2 += v * g.z; a3 += v * g.w;
    }
  }
  pscore[cg][tl][0] = a0; pscore[cg][tl][1] = a1;
  pscore[cg][tl][2] = a2; pscore[cg][tl][3] = a3;
  __syncthreads();
  if (cg == 0 && valid) {
    float z[4];
#pragma unroll
    for (int e = 0; e < 4; e++)
      z[e] = pscore[0][tl][e] + pscore[1][tl][e] + pscore[2][tl][e] +
             pscore[3][tl][e] + gb[e];
    const float mx = fmaxf(fmaxf(z[0], z[1]), fmaxf(z[2], z[3]));
    float s[4]; float sum = 0.f;
#pragma unroll
    for (int e = 0; e < 4; e++) { s[e] = __expf(z[e] - mx); sum += s[e]; }
    const float inv = 1.f / sum;
#pragma unroll
    for (int e = 0; e < 4; e++) s[e] *= inv;
    int e0 = 0; float v0 = s[0];
#pragma unroll
    for (int e = 1; e < 4; e++) if (s[e] > v0) { v0 = s[e]; e0 = e; }
    int e1 = -1; float v1 = -1.f;
#pragma unroll
    for (int e = 0; e < 4; e++) if (e != e0 && s[e] > v1) { v1 = s[e]; e1 = e; }
    const float r = __expf(v1 - v0);
    const float w0 = 1.f / (1.f + r);
    const int m = b * HW_DIM + p0 + tl;
    topw[m * 2] = w0;
    topw[m * 2 + 1] = 1.f - w0;
    atomicOr(&pmask, (1u << e0) | (1u << (4 + e1)));
  }
  __syncthreads();
  if (tid == 0) atomicOr(present, pmask);
  const int nchunk = cnt * 48;
  for (int ci = tid; ci < nchunk; ci += 256) {
    const int row = ci / 48, c8 = ci - row * 48;
    short8 v = *(const short8*)&lxs[row][c8 * 8];
    *(short8*)&xb[(size_t)(b * HW_DIM + p0 + row) * C_DIM + c8 * 8] = v;
  }
}

// ------------- 256-row tile, BK=64, 8-wave, T2+T4+T5+T1 GEMM -----------------
// C[M,BNcols] = A[M,K] * Bw[cols,K]^T ; EPI 0: hdnS epilogue, 1: out epilogue
template <int KDIM, int BN, int EPI>
__global__ __launch_bounds__(512, 2) void gemm256(
    const ushort_t* __restrict__ A, const ushort_t* __restrict__ Bw,
    const float* __restrict__ bias, const float* __restrict__ topw,
    const unsigned int* __restrict__ presentp,
    ushort_t* __restrict__ hOut, float* __restrict__ outp) {
  constexpr int BM = 256, BK = 64;
  constexpr int KT = KDIM / BK;
  constexpr int NTN = (BN == 256 ? NH / 256 : C_DIM / 128);
  constexpr int WM = (BN == 256 ? 128 : 64);   // wave rows (WN = 64 always)
  constexpr int MR = WM / 16;                  // 8 or 4
  constexpr int MR2 = MR / 2;
  constexpr int ASZ = BM * BK;                 // ushorts per A buffer
  constexpr int BSZ = BN * BK;
  constexpr int NLA = BM * BK * 2 / (512 * 16);  // 4 loads/thread for A
  constexpr int NLB = BN * BK * 2 / (512 * 16);  // 4 or 2 for B
  __shared__ ushort_t smem[2 * ASZ + 2 * BSZ];   // 128KB (BN=256) / 96KB

  // T1: bijective XCD swizzle (m204), nwg % 8 != 0 safe
  const int nwg = NTN * (NTOK / BM);
  const int orig = blockIdx.x;
  const int xcd = orig & 7;
  const int qq = nwg >> 3, rr = nwg & 7;
  const int wg = (xcd < rr ? xcd * (qq + 1) : rr * (qq + 1) + (xcd - rr) * qq)
               + (orig >> 3);
  const int mt = wg / NTN, nt = wg % NTN;
  const int m0 = mt * BM, n0 = nt * BN;

  const int tid = threadIdx.x;
  const int lane = tid & 63;
  const int wid = tid >> 6;
  const int wm = (BN == 256) ? (wid >> 2) : (wid >> 1);
  const int wn = (BN == 256) ? (wid & 3) : (wid & 1);

  // T2 both-sides swizzle: LDS stays linear for global_load_lds; the GLOBAL
  // source is pre-swizzled so that ds_read at (row, cb ^ ((row&7)<<4)) is
  // correct and bank-balanced.
  auto stage = [&](int t) {
    ushort_t* dstA = smem + (t & 1) * ASZ;
    ushort_t* dstB = smem + 2 * ASZ + (t & 1) * BSZ;
    const int kb = t * BK;
#pragma unroll
    for (int li = 0; li < NLA; ++li) {
      const int P = (li * 512 + tid) * 16;
      const int row = P >> 7;
      const int cb = (P & 127) ^ ((row & 7) << 4);
      gload_lds16(&A[(size_t)(m0 + row) * KDIM + kb + (cb >> 1)],
                  (char*)dstA + P);
    }
#pragma unroll
    for (int li = 0; li < NLB; ++li) {
      const int P = (li * 512 + tid) * 16;
      const int row = P >> 7;
      const int cb = (P & 127) ^ ((row & 7) << 4);
      gload_lds16(&Bw[(size_t)(n0 + row) * KDIM + kb + (cb >> 1)],
                  (char*)dstB + P);
    }
  };

  f32x4 acc[MR][4] = {};

  stage(0);
  stage(1);
  for (int t = 0; t < KT; ++t) {
    // T4: counted vmcnt — wait own tile-t loads; keep t+1's in flight
    if (t + 1 < KT) {
      if constexpr (NLA + NLB == 8)
        asm volatile("s_waitcnt vmcnt(8)" ::: "memory");
      else
        asm volatile("s_waitcnt vmcnt(6)" ::: "memory");
    } else {
      asm volatile("s_waitcnt vmcnt(0)" ::: "memory");
    }
    __builtin_amdgcn_sched_barrier(0);
    __builtin_amdgcn_s_barrier();
    __builtin_amdgcn_sched_barrier(0);
    const char* Ab = (const char*)(smem + (t & 1) * ASZ);
    const char* Bb = (const char*)(smem + 2 * ASZ + (t & 1) * BSZ);
#pragma unroll
    for (int q = 0; q < 4; ++q) {          // quadrant phases
      const int qm = q >> 1, qn = q & 1;
      short8 av[MR2][2], bv[2][2];
#pragma unroll
      for (int i = 0; i < MR2; ++i)
#pragma unroll
        for (int kk = 0; kk < 2; ++kk) {
          const int row = wm * WM + (qm * MR2 + i) * 16 + (lane & 15);
          const int cb = (kk * 64 + ((lane >> 4) * 16)) ^ ((row & 7) << 4);
          av[i][kk] = *(const short8*)(Ab + row * 128 + cb);
        }
#pragma unroll
      for (int i = 0; i < 2; ++i)
#pragma unroll
        for (int kk = 0; kk < 2; ++kk) {
          const int row = wn * 64 + (qn * 2 + i) * 16 + (lane & 15);
          const int cb = (kk * 64 + ((lane >> 4) * 16)) ^ ((row & 7) << 4);
          bv[i][kk] = *(const short8*)(Bb + row * 128 + cb);
        }
      __builtin_amdgcn_s_setprio(1);       // T5
#pragma unroll
      for (int kk = 0; kk < 2; ++kk)
#pragma unroll
        for (int i = 0; i < MR2; ++i)
#pragma unroll
          for (int j = 0; j < 2; ++j)
            acc[qm * MR2 + i][qn * 2 + j] =
                __builtin_amdgcn_mfma_f32_16x16x32_bf16(
                    av[i][kk], bv[j][kk], acc[qm * MR2 + i][qn * 2 + j], 0, 0, 0);
      __builtin_amdgcn_s_setprio(0);
    }
    __builtin_amdgcn_sched_barrier(0);
    __builtin_amdgcn_s_barrier();          // all waves done reading buf[t&1]
    __builtin_amdgcn_sched_barrier(0);
    if (t + 2 < KT) stage(t + 2);          // refill the vacated buffer
  }

  const unsigned int pm = *presentp;
  if constexpr (EPI == 0) {
    // coef*relu + bf16, LDS transpose (reuse all 128KB as 256x256 bf16)
    ushort_t* tr = smem;
#pragma unroll
    for (int mi = 0; mi < MR; ++mi) {
      const int r0 = wm * WM + mi * 16 + (lane >> 4) * 4;
      const int mg = m0 + r0;
      const float4 t0 = *(const float4*)&topw[mg * 2];
      const float4 t1 = *(const float4*)&topw[mg * 2 + 4];
#pragma unroll
      for (int ni = 0; ni < 4; ++ni) {
        const int cl = wn * 64 + ni * 16 + (lane & 15);
        const int cg = n0 + cl;
        const int e = cg / HID_DIM;        // 16-col frags never cross experts
        const float P0 = (float)((pm >> e) & 1u);
        const float P1 = (float)((pm >> (4 + e)) & 1u);
        const float bvv = bias[cg];
        const float cj[4] = {P0 * t0.x + P1 * t0.y, P0 * t0.z + P1 * t0.w,
                             P0 * t1.x + P1 * t1.y, P0 * t1.z + P1 * t1.w};
#pragma unroll
        for (int j = 0; j < 4; ++j) {
          float v = fmaxf(acc[mi][ni][j] + bvv, 0.f);
          tr[(r0 + j) * 256 + cl] = f2bf(cj[j] * v);
        }
      }
    }
    __syncthreads();
#pragma unroll
    for (int it = 0; it < 16; ++it) {
      const int c = it * 512 + tid;
      const int row = c >> 5, cr = c & 31;
      *(short8*)&hOut[(size_t)(m0 + row) * NH + n0 + cr * 8] =
          *(const short8*)&tr[row * 256 + cr * 8];
    }
  } else {
    float B0[4], B1[4];
#pragma unroll
    for (int ni = 0; ni < 4; ++ni) {
      const int o = n0 + wn * 64 + ni * 16 + (lane & 15);
      float s0 = 0.f, s1 = 0.f;
#pragma unroll
      for (int e2 = 0; e2 < 4; ++e2) {
        const float bb = bias[e2 * C_DIM + o];
        s0 += (float)((pm >> e2) & 1u) * bb;
        s1 += (float)((pm >> (4 + e2)) & 1u) * bb;
      }
      B0[ni] = s0; B1[ni] = s1;
    }
#pragma unroll
    for (int mi = 0; mi < MR; ++mi) {
      const int mg = m0 + wm * WM + mi * 16 + (lane >> 4) * 4;
      const float4 t0 = *(const float4*)&topw[mg * 2];
      const float4 t1 = *(const float4*)&topw[mg * 2 + 4];
      const int bb2 = mg / HW_DIM;
      const int p = mg - bb2 * HW_DIM;     // 4 consecutive p, same batch
#pragma unroll
      for (int ni = 0; ni < 4; ++ni) {
        const int o = n0 + wn * 64 + ni * 16 + (lane & 15);
        float4 v;
        v.x = acc[mi][ni][0] + t0.x * B0[ni] + t0.y * B1[ni];
        v.y = acc[mi][ni][1] + t0.z * B0[ni] + t0.w * B1[ni];
        v.z = acc[mi][ni][2] + t1.x * B0[ni] + t1.y * B1[ni];
        v.w = acc[mi][ni][3] + t1.z * B0[ni] + t1.w * B1[ni];
        *(float4*)&outp[((size_t)bb2 * C_DIM + o) * HW_DIM + p] = v;
      }
    }
  }
}

extern "C" void kernel_launch(void* const* d_in, const int* in_sizes, int n_in,
                              void* d_out, int out_size, void* d_ws, size_t ws_size,
                              hipStream_t stream) {
  const float* x  = (const float*)d_in[0];
  const float* gw = (const float*)d_in[1];
  const float* gb = (const float*)d_in[2];
  const float* w1 = (const float*)d_in[3];
  const float* b1 = (const float*)d_in[4];
  const float* w2 = (const float*)d_in[5];
  const float* b2 = (const float*)d_in[6];
  float* out = (float*)d_out;

  char* ws = (char*)d_ws;
  ushort_t* xb = (ushort_t*)ws;   ws += (size_t)NTOK * C_DIM * 2;
  ushort_t* hdnS = (ushort_t*)ws; ws += (size_t)NTOK * NH * 2;
  ushort_t* W1b = (ushort_t*)ws;  ws += (size_t)NH * C_DIM * 2;
  ushort_t* W2b = (ushort_t*)ws;  ws += (size_t)C_DIM * NH * 2;
  float* topw = (float*)ws;       ws += (size_t)NTOK * 2 * 4;
  unsigned int* present = (unsigned int*)ws;

  prep_kernel<<<dim3((NH * C_DIM) / 256), dim3(256), 0, stream>>>(
      w1, w2, W1b, W2b, present);
  gate_kernel<<<dim3(B_DIM, 13), dim3(256), 0, stream>>>(
      x, gw, gb, xb, topw, present);
  gemm256<C_DIM, 256, 0><<<dim3((NTOK / 256) * 6), dim3(512), 0, stream>>>(
      xb, W1b, b1, topw, present, hdnS, nullptr);
  gemm256<NH, 128, 1><<<dim3((NTOK / 256) * 3), dim3(512), 0, stream>>>(
      hdnS, W2b, b2, topw, present, nullptr, out);
}

// Round 3
// 130.219 us; speedup vs baseline: 1.4298x; 1.1991x over previous
//
#include <hip/hip_runtime.h>
#include <hip/hip_bf16.h>
#include <stdint.h>

// ConvMoE: B=32, C=384, H=W=28, E=4, HID=384, K=2. N tokens = 25088.
// GEMM1: [25088,384] x [1536,384]^T -> hdnS (coef*relu fused, bf16)
// GEMM2: [25088,1536] x [384,1536]^T -> out (fp32) + sum_e coef*b2
#define B_DIM 32
#define C_DIM 384
#define HW_DIM 784
#define E_DIM 4
#define HID_DIM 384
#define NTOK (B_DIM * HW_DIM)   // 25088
#define NH (E_DIM * HID_DIM)    // 1536

using short8 = __attribute__((ext_vector_type(8))) short;
using f32x4  = __attribute__((ext_vector_type(4))) float;
typedef unsigned short ushort_t;

__device__ __forceinline__ ushort_t f2bf(float f) {
  __hip_bfloat16 h = __float2bfloat16(f);
  return __builtin_bit_cast(ushort_t, h);
}

__device__ __forceinline__ void gload_lds16(const void* g, void* l) {
  __builtin_amdgcn_global_load_lds(
      (const __attribute__((address_space(1))) unsigned int*)g,
      (__attribute__((address_space(3))) unsigned int*)l, 16, 0, 0);
}

// ---------------- kernel 1: weight convert (+ zero present mask) -------------
__global__ __launch_bounds__(256) void prep_kernel(
    const float* __restrict__ w1, const float* __restrict__ w2,
    ushort_t* __restrict__ W1b, ushort_t* __restrict__ W2b,
    unsigned int* __restrict__ present) {
  int i = blockIdx.x * 256 + threadIdx.x;
  if (i == 0) *present = 0u;
  if (i < NH * C_DIM) {
    W1b[i] = f2bf(w1[i]);                       // [e*HID+d][c]
    int o = i / NH;
    int r = i - o * NH;
    int e = r / HID_DIM;
    int k = r - e * HID_DIM;
    W2b[i] = f2bf(w2[((size_t)e * C_DIM + o) * HID_DIM + k]);  // [o][e*384+k]
  }
}

// ---------------- kernel 2: gate + softmax + top2 + x -> bf16 [N][C] ---------
__global__ __launch_bounds__(256) void gate_kernel(
    const float* __restrict__ x, const float* __restrict__ gw,
    const float* __restrict__ gb, ushort_t* __restrict__ xb,
    float* __restrict__ topw, unsigned int* __restrict__ present) {
  __shared__ __align__(16) ushort_t lxs[64][392];
  __shared__ float pscore[4][64][4];
  __shared__ unsigned int pmask;
  const int b = blockIdx.x;
  const int p0 = blockIdx.y * 64;
  const int cnt = min(64, HW_DIM - p0);
  const int tid = threadIdx.x;
  const int cg = tid >> 6, tl = tid & 63;
  if (tid == 0) pmask = 0u;
  float a0 = 0.f, a1 = 0.f, a2 = 0.f, a3 = 0.f;
  const bool valid = tl < cnt;
  if (valid) {
    const float* xp = x + (size_t)b * C_DIM * HW_DIM + p0 + tl;
    for (int c = cg; c < C_DIM; c += 4) {
      const float v = xp[(size_t)c * HW_DIM];
      lxs[tl][c] = f2bf(v);
      const float4 g = *(const float4*)&gw[c * 4];
      a0 += v * g.x; a1 += v * g.y; a2 += v * g.z; a3 += v * g.w;
    }
  }
  pscore[cg][tl][0] = a0; pscore[cg][tl][1] = a1;
  pscore[cg][tl][2] = a2; pscore[cg][tl][3] = a3;
  __syncthreads();
  if (cg == 0 && valid) {
    float z[4];
#pragma unroll
    for (int e = 0; e < 4; e++)
      z[e] = pscore[0][tl][e] + pscore[1][tl][e] + pscore[2][tl][e] +
             pscore[3][tl][e] + gb[e];
    const float mx = fmaxf(fmaxf(z[0], z[1]), fmaxf(z[2], z[3]));
    float s[4]; float sum = 0.f;
#pragma unroll
    for (int e = 0; e < 4; e++) { s[e] = __expf(z[e] - mx); sum += s[e]; }
    const float inv = 1.f / sum;
#pragma unroll
    for (int e = 0; e < 4; e++) s[e] *= inv;
    int e0 = 0; float v0 = s[0];
#pragma unroll
    for (int e = 1; e < 4; e++) if (s[e] > v0) { v0 = s[e]; e0 = e; }
    int e1 = -1; float v1 = -1.f;
#pragma unroll
    for (int e = 0; e < 4; e++) if (e != e0 && s[e] > v1) { v1 = s[e]; e1 = e; }
    const float r = __expf(v1 - v0);
    const float w0 = 1.f / (1.f + r);
    const int m = b * HW_DIM + p0 + tl;
    topw[m * 2] = w0;
    topw[m * 2 + 1] = 1.f - w0;
    atomicOr(&pmask, (1u << e0) | (1u << (4 + e1)));
  }
  __syncthreads();
  if (tid == 0) atomicOr(present, pmask);
  const int nchunk = cnt * 48;
  for (int ci = tid; ci < nchunk; ci += 256) {
    const int row = ci / 48, c8 = ci - row * 48;
    short8 v = *(const short8*)&lxs[row][c8 * 8];
    *(short8*)&xb[(size_t)(b * HW_DIM + p0 + row) * C_DIM + c8 * 8] = v;
  }
}

// -------- 128x128 tile, BK=64, 4 waves, dbuf 64KB (2 blk/CU), T1/T2/T4/T5 ----
// C[M,128] = A[M,K] * Bw[cols,K]^T ; EPI 0: hdnS epilogue, 1: out epilogue
template <int KDIM, int EPI>
__global__ __launch_bounds__(256, 2) void gemm128(
    const ushort_t* __restrict__ A, const ushort_t* __restrict__ Bw,
    const float* __restrict__ bias, const float* __restrict__ topw,
    const unsigned int* __restrict__ presentp,
    ushort_t* __restrict__ hOut, float* __restrict__ outp) {
  constexpr int BM = 128, BN = 128, BK = 64;
  constexpr int KT = KDIM / BK;
  constexpr int NTN = (EPI == 0 ? NH / BN : C_DIM / BN);  // 12 or 3
  constexpr int ASZ = BM * BK;                 // 8192 ushorts = 16 KB
  __shared__ ushort_t smem[4 * ASZ];           // A0,A1,B0,B1 = 64 KB

  // T1: bijective XCD swizzle (m204); consecutive wg share mt -> same-XCD L2
  const int nwg = NTN * (NTOK / BM);
  const int orig = blockIdx.x;
  const int xcd = orig & 7;
  const int qq = nwg >> 3, rr = nwg & 7;
  const int wg = (xcd < rr ? xcd * (qq + 1) : rr * (qq + 1) + (xcd - rr) * qq)
               + (orig >> 3);
  const int mt = wg / NTN, nt = wg % NTN;
  const int m0 = mt * BM, n0 = nt * BN;

  const int tid = threadIdx.x;
  const int lane = tid & 63;
  const int wid = tid >> 6;
  const int wm = wid >> 1, wn = wid & 1;       // wave tile 64x64

  // T2 both-sides swizzle: linear LDS dest for global_load_lds, pre-swizzled
  // global source; ds_read applies the same XOR.
  auto stage = [&](int t) {
    ushort_t* dstA = smem + (t & 1) * ASZ;
    ushort_t* dstB = smem + 2 * ASZ + (t & 1) * ASZ;
    const int kb = t * BK;
#pragma unroll
    for (int li = 0; li < 4; ++li) {
      const int P = (li * 256 + tid) * 16;     // byte offset in 16KB buffer
      const int row = P >> 7;
      const int cb = (P & 127) ^ ((row & 7) << 4);
      gload_lds16(&A[(size_t)(m0 + row) * KDIM + kb + (cb >> 1)],
                  (char*)dstA + P);
    }
#pragma unroll
    for (int li = 0; li < 4; ++li) {
      const int P = (li * 256 + tid) * 16;
      const int row = P >> 7;
      const int cb = (P & 127) ^ ((row & 7) << 4);
      gload_lds16(&Bw[(size_t)(n0 + row) * KDIM + kb + (cb >> 1)],
                  (char*)dstB + P);
    }
  };

  f32x4 acc[4][4] = {};

  stage(0);
  stage(1);
  for (int t = 0; t < KT; ++t) {
    // T4: counted vmcnt — tile t's 8 loads arrived; keep later tiles in flight
    if (t + 1 < KT)
      asm volatile("s_waitcnt vmcnt(8)" ::: "memory");
    else
      asm volatile("s_waitcnt vmcnt(0)" ::: "memory");
    __builtin_amdgcn_sched_barrier(0);
    __builtin_amdgcn_s_barrier();
    __builtin_amdgcn_sched_barrier(0);
    const char* Ab = (const char*)(smem + (t & 1) * ASZ);
    const char* Bb = (const char*)(smem + 2 * ASZ + (t & 1) * ASZ);
    short8 av[4][2], bv[4][2];                 // hoisted: each frag read ONCE
#pragma unroll
    for (int i = 0; i < 4; ++i)
#pragma unroll
      for (int kk = 0; kk < 2; ++kk) {
        const int row = wm * 64 + i * 16 + (lane & 15);
        const int cb = (kk * 64 + ((lane >> 4) * 16)) ^ ((row & 7) << 4);
        av[i][kk] = *(const short8*)(Ab + row * 128 + cb);
      }
#pragma unroll
    for (int i = 0; i < 4; ++i)
#pragma unroll
      for (int kk = 0; kk < 2; ++kk) {
        const int row = wn * 64 + i * 16 + (lane & 15);
        const int cb = (kk * 64 + ((lane >> 4) * 16)) ^ ((row & 7) << 4);
        bv[i][kk] = *(const short8*)(Bb + row * 128 + cb);
      }
    __builtin_amdgcn_s_setprio(1);             // T5
#pragma unroll
    for (int kk = 0; kk < 2; ++kk)
#pragma unroll
      for (int i = 0; i < 4; ++i)
#pragma unroll
        for (int j = 0; j < 4; ++j)
          acc[i][j] = __builtin_amdgcn_mfma_f32_16x16x32_bf16(
              av[i][kk], bv[j][kk], acc[i][j], 0, 0, 0);
    __builtin_amdgcn_s_setprio(0);
    __builtin_amdgcn_sched_barrier(0);
    __builtin_amdgcn_s_barrier();              // all waves done with buf[t&1]
    __builtin_amdgcn_sched_barrier(0);
    if (t + 2 < KT) stage(t + 2);
  }

  const unsigned int pm = *presentp;
  if constexpr (EPI == 0) {
    // coef*relu + bf16, LDS transpose (smem reused as 128x128 bf16 = 32 KB)
    ushort_t* tr = smem;
    const int e = n0 / HID_DIM;                // 128-col tile: single expert
    const float P0 = (float)((pm >> e) & 1u);
    const float P1 = (float)((pm >> (4 + e)) & 1u);
#pragma unroll
    for (int mi = 0; mi < 4; ++mi) {
      const int r0 = wm * 64 + mi * 16 + (lane >> 4) * 4;
      const int mg = m0 + r0;
      const float4 t0 = *(const float4*)&topw[mg * 2];
      const float4 t1 = *(const float4*)&topw[mg * 2 + 4];
      const float cj[4] = {P0 * t0.x + P1 * t0.y, P0 * t0.z + P1 * t0.w,
                           P0 * t1.x + P1 * t1.y, P0 * t1.z + P1 * t1.w};
#pragma unroll
      for (int ni = 0; ni < 4; ++ni) {
        const int cl = wn * 64 + ni * 16 + (lane & 15);
        const float bvv = bias[n0 + cl];
#pragma unroll
        for (int j = 0; j < 4; ++j) {
          float v = fmaxf(acc[mi][ni][j] + bvv, 0.f);
          tr[(r0 + j) * 128 + cl] = f2bf(cj[j] * v);
        }
      }
    }
    __syncthreads();
#pragma unroll
    for (int it = 0; it < 8; ++it) {
      const int c = it * 256 + tid;
      const int row = c >> 4, cr = c & 15;
      *(short8*)&hOut[(size_t)(m0 + row) * NH + n0 + cr * 8] =
          *(const short8*)&tr[row * 128 + cr * 8];
    }
  } else {
    float B0[4], B1[4];
#pragma unroll
    for (int ni = 0; ni < 4; ++ni) {
      const int o = n0 + wn * 64 + ni * 16 + (lane & 15);
      float s0 = 0.f, s1 = 0.f;
#pragma unroll
      for (int e2 = 0; e2 < 4; ++e2) {
        const float bb = bias[e2 * C_DIM + o];
        s0 += (float)((pm >> e2) & 1u) * bb;
        s1 += (float)((pm >> (4 + e2)) & 1u) * bb;
      }
      B0[ni] = s0; B1[ni] = s1;
    }
#pragma unroll
    for (int mi = 0; mi < 4; ++mi) {
      const int mg = m0 + wm * 64 + mi * 16 + (lane >> 4) * 4;
      const float4 t0 = *(const float4*)&topw[mg * 2];
      const float4 t1 = *(const float4*)&topw[mg * 2 + 4];
      const int bb2 = mg / HW_DIM;
      const int p = mg - bb2 * HW_DIM;         // 4 consecutive p, same batch
#pragma unroll
      for (int ni = 0; ni < 4; ++ni) {
        const int o = n0 + wn * 64 + ni * 16 + (lane & 15);
        float4 v;
        v.x = acc[mi][ni][0] + t0.x * B0[ni] + t0.y * B1[ni];
        v.y = acc[mi][ni][1] + t0.z * B0[ni] + t0.w * B1[ni];
        v.z = acc[mi][ni][2] + t1.x * B0[ni] + t1.y * B1[ni];
        v.w = acc[mi][ni][3] + t1.z * B0[ni] + t1.w * B1[ni];
        *(float4*)&outp[((size_t)bb2 * C_DIM + o) * HW_DIM + p] = v;
      }
    }
  }
}

extern "C" void kernel_launch(void* const* d_in, const int* in_sizes, int n_in,
                              void* d_out, int out_size, void* d_ws, size_t ws_size,
                              hipStream_t stream) {
  const float* x  = (const float*)d_in[0];
  const float* gw = (const float*)d_in[1];
  const float* gb = (const float*)d_in[2];
  const float* w1 = (const float*)d_in[3];
  const float* b1 = (const float*)d_in[4];
  const float* w2 = (const float*)d_in[5];
  const float* b2 = (const float*)d_in[6];
  float* out = (float*)d_out;

  char* ws = (char*)d_ws;
  ushort_t* xb = (ushort_t*)ws;   ws += (size_t)NTOK * C_DIM * 2;
  ushort_t* hdnS = (ushort_t*)ws; ws += (size_t)NTOK * NH * 2;
  ushort_t* W1b = (ushort_t*)ws;  ws += (size_t)NH * C_DIM * 2;
  ushort_t* W2b = (ushort_t*)ws;  ws += (size_t)C_DIM * NH * 2;
  float* topw = (float*)ws;       ws += (size_t)NTOK * 2 * 4;
  unsigned int* present = (unsigned int*)ws;

  prep_kernel<<<dim3((NH * C_DIM) / 256), dim3(256), 0, stream>>>(
      w1, w2, W1b, W2b, present);
  gate_kernel<<<dim3(B_DIM, 13), dim3(256), 0, stream>>>(
      x, gw, gb, xb, topw, present);
  gemm128<C_DIM, 0><<<dim3((NTOK / 128) * (NH / 128)), dim3(256), 0, stream>>>(
      xb, W1b, b1, topw, present, hdnS, nullptr);
  gemm128<NH, 1><<<dim3((NTOK / 128) * (C_DIM / 128)), dim3(256), 0, stream>>>(
      hdnS, W2b, b2, topw, present, nullptr, out);
}